// Round 18
// baseline (310.451 us; speedup 1.0000x reference)
//
#include <hip/hip_runtime.h>
#include <hip/hip_bf16.h>
#include <cstdio>
#include <cstdint>

#define DD 64
#define EPT 8

typedef __attribute__((ext_vector_type(8))) short bf16x8;
typedef __attribute__((ext_vector_type(4))) float f32x4;

__device__ __forceinline__ short f2b(float f) {
    __hip_bfloat16 h = __float2bfloat16(f);
    return __builtin_bit_cast(short, h);
}
__device__ __forceinline__ float b2f(unsigned short s) {
    unsigned u = ((unsigned)s) << 16;
    return __builtin_bit_cast(float, u);
}

// ---------------- transform via MFMA: y = bf16(x) @ bf16(W_conv) + b -> bf16 ----------------
__global__ void transform_mfma(const float* __restrict__ xt, const short* __restrict__ WTt,
                               const float* __restrict__ bt, unsigned short* __restrict__ yt, int ntk,
                               const float* __restrict__ xi, const short* __restrict__ WTi,
                               const float* __restrict__ bi, unsigned short* __restrict__ yi, int nik) {
    const float* x; const short* WT; const float* b; unsigned short* y; int n;
    if (blockIdx.y == 0) { x = xt; WT = WTt; b = bt; y = yt; n = ntk; }
    else                 { x = xi; WT = WTi; b = bi; y = yi; n = nik; }
    const int tid = threadIdx.x;
    const int wave = tid >> 6, lane = tid & 63;
    const int lr = lane & 15, lg = lane >> 4;
    const int row0 = blockIdx.x * 256 + wave * 64;
    if (row0 >= n) return;

    bf16x8 B[4][2];
    #pragma unroll
    for (int nt = 0; nt < 4; ++nt)
        #pragma unroll
        for (int ks = 0; ks < 2; ++ks)
            B[nt][ks] = *(const bf16x8*)&WT[(size_t)(nt * 16 + lr) * 64 + ks * 32 + lg * 8];
    float bias[4];
    #pragma unroll
    for (int nt = 0; nt < 4; ++nt) bias[nt] = b[nt * 16 + lr];

    f32x4 acc[4][4];
    f32x4 z4 = {0.f, 0.f, 0.f, 0.f};
    #pragma unroll
    for (int rt = 0; rt < 4; ++rt)
        #pragma unroll
        for (int nt = 0; nt < 4; ++nt) acc[rt][nt] = z4;

    #pragma unroll
    for (int rt = 0; rt < 4; ++rt) {
        int r = row0 + rt * 16 + lr;
        #pragma unroll
        for (int ks = 0; ks < 2; ++ks) {
            bf16x8 af = {0, 0, 0, 0, 0, 0, 0, 0};
            if (r < n) {
                const float* p = &x[(size_t)r * 64 + ks * 32 + lg * 8];
                float4 u0 = *(const float4*)p;
                float4 u1 = *(const float4*)(p + 4);
                af[0] = f2b(u0.x); af[1] = f2b(u0.y); af[2] = f2b(u0.z); af[3] = f2b(u0.w);
                af[4] = f2b(u1.x); af[5] = f2b(u1.y); af[6] = f2b(u1.z); af[7] = f2b(u1.w);
            }
            #pragma unroll
            for (int nt = 0; nt < 4; ++nt)
                acc[rt][nt] = __builtin_amdgcn_mfma_f32_16x16x32_bf16(af, B[nt][ks], acc[rt][nt], 0, 0, 0);
        }
    }
    #pragma unroll
    for (int rt = 0; rt < 4; ++rt)
        #pragma unroll
        for (int j = 0; j < 4; ++j) {
            int r = row0 + rt * 16 + lg * 4 + j;
            if (r >= n) continue;
            #pragma unroll
            for (int nt = 0; nt < 4; ++nt)
                y[(size_t)r * 64 + nt * 16 + lr] = (unsigned short)f2b(acc[rt][nt][j] + bias[nt]);
        }
}

// ---------------- CSR build: XCD-partitioned histogram (int4-vectorized edge scan) ----------------
__global__ void hist_part(const int* __restrict__ dti, const int* __restrict__ dit, int E,
                          int* __restrict__ rin, int* __restrict__ rtr, int nin, int ntr) {
    const int* dst = blockIdx.y ? dit : dti;
    int* row       = blockIdx.y ? rtr : rin;
    int n          = blockIdx.y ? ntr : nin;
    int part  = blockIdx.x & 7;
    int chunk = blockIdx.x >> 3;
    int psz = (n + 7) >> 3;
    int lo = part * psz, hi = min(n, lo + psz);
    int base = chunk * (256 * EPT) + threadIdx.x * EPT;   // 8 contiguous edges/thread
    if (base + EPT <= E) {
        int4 d0 = *(const int4*)&dst[base];
        int4 d1 = *(const int4*)&dst[base + 4];
        int d[8] = { d0.x, d0.y, d0.z, d0.w, d1.x, d1.y, d1.z, d1.w };
        #pragma unroll
        for (int k = 0; k < 8; ++k)
            if (d[k] >= lo && d[k] < hi) atomicAdd(&row[d[k] + 1], 1);
    } else {
        for (int k = 0; k < EPT; ++k) {
            int i = base + k;
            if (i < E) {
                int dd = dst[i];
                if (dd >= lo && dd < hi) atomicAdd(&row[dd + 1], 1);
            }
        }
    }
}

// 3-phase multi-block scan over two arrays at once (blockIdx.y selects array).
#define SCHUNK 4096
__global__ void scan_p1(int* __restrict__ rowA, int nA, int* __restrict__ bsA,
                        int* __restrict__ rowB, int nB, int* __restrict__ bsB) {
    int* row = blockIdx.y ? rowB : rowA;
    int n    = blockIdx.y ? nB : nA;
    int* bs  = blockIdx.y ? bsB : bsA;
    int b = blockIdx.x, t = threadIdx.x;
    int base = 1 + b * SCHUNK;
    __shared__ int wsum[4];
    if (base > n) { if (t == 0) bs[b] = 0; return; }
    int idx0 = base + t * 16;
    int v[16];
    int s = 0;
    #pragma unroll
    for (int k = 0; k < 16; ++k) {
        int i = idx0 + k;
        int x = (i <= n) ? row[i] : 0;
        s += x; v[k] = s;
    }
    int lane = t & 63, wid = t >> 6;
    int ssc = s;
    #pragma unroll
    for (int off = 1; off < 64; off <<= 1) {
        int u = __shfl_up(ssc, off, 64);
        if (lane >= off) ssc += u;
    }
    if (lane == 63) wsum[wid] = ssc;
    __syncthreads();
    int wprev = 0;
    #pragma unroll
    for (int w = 0; w < 4; ++w) if (w < wid) wprev += wsum[w];
    int tpre = ssc - s + wprev;
    #pragma unroll
    for (int k = 0; k < 16; ++k) {
        int i = idx0 + k;
        if (i <= n) row[i] = v[k] + tpre;
    }
    if (t == 0) bs[b] = wsum[0] + wsum[1] + wsum[2] + wsum[3];
}

__global__ void scan_p2(int* __restrict__ bsA, int* __restrict__ bsB) {
    int* bs = blockIdx.x ? bsB : bsA;
    int lane = threadIdx.x;   // 64 threads
    int v = bs[lane];
    int s = v;
    #pragma unroll
    for (int off = 1; off < 64; off <<= 1) {
        int u = __shfl_up(s, off, 64);
        if (lane >= off) s += u;
    }
    bs[lane] = s - v;   // exclusive
}

__global__ void scan_p3(int* __restrict__ rowA, int* __restrict__ curA, int nA,
                        const int* __restrict__ bsA,
                        int* __restrict__ rowB, int* __restrict__ curB, int nB,
                        const int* __restrict__ bsB) {
    int* row = blockIdx.y ? rowB : rowA;
    int* cur = blockIdx.y ? curB : curA;
    int n    = blockIdx.y ? nB : nA;
    const int* bs = blockIdx.y ? bsB : bsA;
    int b = blockIdx.x, t = threadIdx.x;
    int base = 1 + b * SCHUNK;
    if (b == 0 && t == 0) { row[0] = 0; cur[0] = 0; }
    if (base > n) return;
    int off = bs[b];
    int end = min(base + SCHUNK - 1, n);
    for (int i = base + t; i <= end; i += 256) {
        int val = row[i] + off;
        row[i] = val;
        if (i < n) cur[i] = val;
    }
}

// ---------------- XCD-partitioned permute (int4-vectorized dst scan; stores src<<6) ----------------
__global__ void permute_part(const int* __restrict__ sti, const int* __restrict__ dti,
                             int* __restrict__ cin, int* __restrict__ oti,
                             const int* __restrict__ sit, const int* __restrict__ dit,
                             int* __restrict__ ctr, int* __restrict__ oit,
                             int E, int nin, int ntr) {
    const int* src; const int* dst; int* cur; int* col; int n;
    if (blockIdx.y == 0) { src = sti; dst = dti; cur = cin; col = oti; n = nin; }
    else                 { src = sit; dst = dit; cur = ctr; col = oit; n = ntr; }
    int part  = blockIdx.x & 7;
    int chunk = blockIdx.x >> 3;
    int psz = (n + 7) >> 3;
    int lo = part * psz, hi = min(n, lo + psz);
    int base = chunk * (256 * EPT) + threadIdx.x * EPT;   // 8 contiguous edges/thread
    if (base + EPT <= E) {
        int4 d0 = *(const int4*)&dst[base];
        int4 d1 = *(const int4*)&dst[base + 4];
        int d[8] = { d0.x, d0.y, d0.z, d0.w, d1.x, d1.y, d1.z, d1.w };
        #pragma unroll
        for (int k = 0; k < 8; ++k)
            if (d[k] >= lo && d[k] < hi) {
                int p = atomicAdd(&cur[d[k]], 1);
                col[p] = src[base + k] << 6;   // pre-scaled row offset
            }
    } else {
        for (int k = 0; k < EPT; ++k) {
            int i = base + k;
            if (i < E) {
                int dd = dst[i];
                if (dd >= lo && dd < hi) {
                    int p = atomicAdd(&cur[dd], 1);
                    col[p] = src[i] << 6;
                }
            }
        }
    }
}

// ---------------- aggregate: wave = node; 4 edge slots x 16 lanes; 4-deep gather pipeline ----------------
// flag = (degree == 0): for deg>0, sum(|mean|+|sum|+|max|)==0 requires all 192 f32 values
// exactly 0 (measure-zero with continuous data) -> equivalent, saves the 28-op reduce.
__global__ void aggregate2(const unsigned short* __restrict__ yt, const int* __restrict__ row_in,
                           const int* __restrict__ col_ti, short* __restrict__ tot_in,
                           int* __restrict__ flag_in, int n_in,
                           const unsigned short* __restrict__ yi, const int* __restrict__ row_tr,
                           const int* __restrict__ col_it, short* __restrict__ tot_tr,
                           int* __restrict__ flag_tr, int n_tr) {
    const unsigned short* y; const int* row; const int* col; short* tot; int* flag; int n;
    if (blockIdx.y == 0) { y = yt; row = row_in; col = col_ti; tot = tot_in; flag = flag_in; n = n_in; }
    else                 { y = yi; row = row_tr; col = col_it; tot = tot_tr; flag = flag_tr; n = n_tr; }
    int wv = (int)((blockIdx.x * (size_t)blockDim.x + threadIdx.x) >> 6);
    if (wv >= n) return;
    int lane = threadIdx.x & 63;
    int sub = lane >> 4;        // edge slot 0..3
    int dl4 = (lane & 15) * 4;  // dims dl4..dl4+3
    int e0 = row[wv], e1 = row[wv + 1];
    float s0 = 0.f, s1 = 0.f, s2 = 0.f, s3 = 0.f;
    float m0 = 0.f, m1 = 0.f, m2 = 0.f, m3 = 0.f;   // init 0 == max(0, segmax)
    int e = e0 + sub;
    for (; e + 12 < e1; e += 16) {
        int c0 = col[e], c1 = col[e + 4], c2 = col[e + 8], c3 = col[e + 12];
        ushort4 u0 = *(const ushort4*)&y[(size_t)(unsigned)(c0 + dl4)];
        ushort4 u1 = *(const ushort4*)&y[(size_t)(unsigned)(c1 + dl4)];
        ushort4 u2 = *(const ushort4*)&y[(size_t)(unsigned)(c2 + dl4)];
        ushort4 u3 = *(const ushort4*)&y[(size_t)(unsigned)(c3 + dl4)];
        float f;
        f = b2f(u0.x); s0 += f; m0 = fmaxf(m0, f);
        f = b2f(u0.y); s1 += f; m1 = fmaxf(m1, f);
        f = b2f(u0.z); s2 += f; m2 = fmaxf(m2, f);
        f = b2f(u0.w); s3 += f; m3 = fmaxf(m3, f);
        f = b2f(u1.x); s0 += f; m0 = fmaxf(m0, f);
        f = b2f(u1.y); s1 += f; m1 = fmaxf(m1, f);
        f = b2f(u1.z); s2 += f; m2 = fmaxf(m2, f);
        f = b2f(u1.w); s3 += f; m3 = fmaxf(m3, f);
        f = b2f(u2.x); s0 += f; m0 = fmaxf(m0, f);
        f = b2f(u2.y); s1 += f; m1 = fmaxf(m1, f);
        f = b2f(u2.z); s2 += f; m2 = fmaxf(m2, f);
        f = b2f(u2.w); s3 += f; m3 = fmaxf(m3, f);
        f = b2f(u3.x); s0 += f; m0 = fmaxf(m0, f);
        f = b2f(u3.y); s1 += f; m1 = fmaxf(m1, f);
        f = b2f(u3.z); s2 += f; m2 = fmaxf(m2, f);
        f = b2f(u3.w); s3 += f; m3 = fmaxf(m3, f);
    }
    for (; e + 4 < e1; e += 8) {
        int c0 = col[e], c1 = col[e + 4];
        ushort4 u0 = *(const ushort4*)&y[(size_t)(unsigned)(c0 + dl4)];
        ushort4 u1 = *(const ushort4*)&y[(size_t)(unsigned)(c1 + dl4)];
        float f;
        f = b2f(u0.x); s0 += f; m0 = fmaxf(m0, f);
        f = b2f(u0.y); s1 += f; m1 = fmaxf(m1, f);
        f = b2f(u0.z); s2 += f; m2 = fmaxf(m2, f);
        f = b2f(u0.w); s3 += f; m3 = fmaxf(m3, f);
        f = b2f(u1.x); s0 += f; m0 = fmaxf(m0, f);
        f = b2f(u1.y); s1 += f; m1 = fmaxf(m1, f);
        f = b2f(u1.z); s2 += f; m2 = fmaxf(m2, f);
        f = b2f(u1.w); s3 += f; m3 = fmaxf(m3, f);
    }
    for (; e < e1; e += 4) {
        int c0 = col[e];
        ushort4 u0 = *(const ushort4*)&y[(size_t)(unsigned)(c0 + dl4)];
        float f;
        f = b2f(u0.x); s0 += f; m0 = fmaxf(m0, f);
        f = b2f(u0.y); s1 += f; m1 = fmaxf(m1, f);
        f = b2f(u0.z); s2 += f; m2 = fmaxf(m2, f);
        f = b2f(u0.w); s3 += f; m3 = fmaxf(m3, f);
    }
    #pragma unroll
    for (int off = 16; off <= 32; off <<= 1) {
        s0 += __shfl_xor(s0, off, 64); s1 += __shfl_xor(s1, off, 64);
        s2 += __shfl_xor(s2, off, 64); s3 += __shfl_xor(s3, off, 64);
        m0 = fmaxf(m0, __shfl_xor(m0, off, 64)); m1 = fmaxf(m1, __shfl_xor(m1, off, 64));
        m2 = fmaxf(m2, __shfl_xor(m2, off, 64)); m3 = fmaxf(m3, __shfl_xor(m3, off, 64));
    }
    float dn = fmaxf((float)(e1 - e0), 1.0f);
    float a0 = s0 / dn, a1 = s1 / dn, a2 = s2 / dn, a3 = s3 / dn;
    size_t bse = (size_t)wv * 192;
    if (sub == 0) {
        short4 hm = { f2b(a0), f2b(a1), f2b(a2), f2b(a3) };
        short4 hs = { f2b(s0), f2b(s1), f2b(s2), f2b(s3) };
        short4 hx = { f2b(m0), f2b(m1), f2b(m2), f2b(m3) };
        *(short4*)&tot[bse + dl4]       = hm;
        *(short4*)&tot[bse + 64 + dl4]  = hs;
        *(short4*)&tot[bse + 128 + dl4] = hx;
    }
    if (lane == 0) flag[wv] = (e1 == e0) ? 1 : 0;
}

// ---------------- prep all 8 weights: W[K][N] f32 -> W^T[N][K] bf16 ----------------
__global__ void prep_all(const float* __restrict__ Wat_t, const float* __restrict__ Wag_t,
                         const float* __restrict__ Wsf_t, const float* __restrict__ Wcv_t,
                         const float* __restrict__ Wat_i, const float* __restrict__ Wag_i,
                         const float* __restrict__ Wsf_i, const float* __restrict__ Wcv_i,
                         short* __restrict__ oat_t, short* __restrict__ oag_t,
                         short* __restrict__ osf_t, short* __restrict__ ocv_t,
                         short* __restrict__ oat_i, short* __restrict__ oag_i,
                         short* __restrict__ osf_i, short* __restrict__ ocv_i) {
    int i = blockIdx.x * blockDim.x + threadIdx.x;
    if (i >= 122880) return;
    int side = 0;
    if (i >= 61440) { side = 1; i -= 61440; }
    const float* W; short* o; int K, N;
    if (i < 36864)      { W = side ? Wat_i : Wat_t; o = side ? oat_i : oat_t; K = 192; N = 192; }
    else if (i < 49152) { i -= 36864; W = side ? Wag_i : Wag_t; o = side ? oag_i : oag_t; K = 192; N = 64; }
    else if (i < 57344) { i -= 49152; W = side ? Wsf_i : Wsf_t; o = side ? osf_i : osf_t; K = 128; N = 64; }
    else                { i -= 57344; W = side ? Wcv_i : Wcv_t; o = side ? ocv_i : ocv_t; K = 64;  N = 64; }
    int n = i / K, k = i - n * K;
    o[(size_t)n * K + k] = f2b(W[(size_t)k * N + n]);
}

// ---------------- fused dense tail (exact r10 shape): wave = column strip, 64 rows each ----------------
struct FusedArgs {
    const short* tot[2]; const float* x[2];
    const short* watt[2]; const float* batt[2];
    const short* waggr[2]; const float* baggr[2];
    const short* wself[2]; const float* bself[2];
    const int* flag[2]; float* out[2]; int M[2];
};

__launch_bounds__(256, 2)
__global__ void fused_dense(FusedArgs a) {
    const int side = blockIdx.y;
    const int M = a.M[side];
    const int row0 = blockIdx.x * 64;
    if (row0 >= M) return;
    const short* tot = a.tot[side]; const float* x = a.x[side];
    const short* WattT = a.watt[side]; const float* b_att = a.batt[side];
    const short* WaggrT = a.waggr[side]; const float* b_aggr = a.baggr[side];
    const short* WselfT = a.wself[side]; const float* b_self = a.bself[side];
    const int* flag = a.flag[side]; float* out = a.out[side];

    __shared__ __align__(16) short ldsA[64 * 200];   // A tile; reused as [64][136] A3
    __shared__ __align__(16) float ldsP[64][4];      // rowmask partials per wave
    __shared__ int ldsFlag[64];

    const int tid = threadIdx.x;
    const int wave = tid >> 6, lane = tid & 63;
    const int lr = lane & 15, lg = lane >> 4;
    f32x4 z4 = {0.f, 0.f, 0.f, 0.f};

    // ---- preload GEMM1 B fragments ----
    bf16x8 B1[3][6];
    #pragma unroll
    for (int nt = 0; nt < 3; ++nt)
        #pragma unroll
        for (int ks = 0; ks < 6; ++ks)
            B1[nt][ks] = *(const bf16x8*)&WattT[(size_t)((wave * 3 + nt) * 16 + lr) * 192 + ks * 32 + lg * 8];

    // ---- stage A tile: bf16 tot rows, stride 200 shorts ----
    #pragma unroll
    for (int q = 0; q < 6; ++q) {
        int i = tid + q * 256;
        int r = i / 24, c = i % 24;
        int rg = row0 + r;
        uint4 v = {0u, 0u, 0u, 0u};
        if (rg < M) v = ((const uint4*)tot)[(size_t)rg * 24 + c];
        *(uint4*)&ldsA[r * 200 + c * 8] = v;
    }
    if (tid < 64) ldsFlag[tid] = (row0 + tid < M) ? flag[row0 + tid] : 1;
    __syncthreads();                                    // S1: A staged, B1 arrived

    // ---- GEMM1: all 64 rows x 48 cols ----
    f32x4 acc1[4][3];
    #pragma unroll
    for (int rt = 0; rt < 4; ++rt)
        #pragma unroll
        for (int nt = 0; nt < 3; ++nt) acc1[rt][nt] = z4;
    #pragma unroll
    for (int ks = 0; ks < 6; ++ks) {
        #pragma unroll
        for (int rt = 0; rt < 4; ++rt) {
            bf16x8 af = *(const bf16x8*)&ldsA[(rt * 16 + lr) * 200 + ks * 32 + lg * 8];
            #pragma unroll
            for (int nt = 0; nt < 3; ++nt)
                acc1[rt][nt] = __builtin_amdgcn_mfma_f32_16x16x32_bf16(af, B1[nt][ks], acc1[rt][nt], 0, 0, 0);
        }
    }
    // issue GEMM2 B fragments (drained at S2)
    bf16x8 B2[6];
    #pragma unroll
    for (int ks = 0; ks < 6; ++ks)
        B2[ks] = *(const bf16x8*)&WaggrT[(size_t)(wave * 16 + lr) * 192 + ks * 32 + lg * 8];
    __syncthreads();                                    // S2: all GEMM1 A-reads done

    // ---- gate epilogue: A2 = A * sigmoid(G + b_att) on this wave's 48 cols ----
    #pragma unroll
    for (int nt = 0; nt < 3; ++nt) {
        int colg = (wave * 3 + nt) * 16 + lr;
        float bb = b_att[colg];
        #pragma unroll
        for (int rt = 0; rt < 4; ++rt)
            #pragma unroll
            for (int j = 0; j < 4; ++j) {
                int rloc = rt * 16 + lg * 4 + j;
                float g = acc1[rt][nt][j] + bb;
                float sg = 1.f / (1.f + __expf(-g));
                int idx = rloc * 200 + colg;
                ldsA[idx] = f2b(b2f((unsigned short)ldsA[idx]) * sg);
            }
    }
    __syncthreads();                                    // S3: gate done, B2 arrived

    // issue GEMM3 B fragments + x rows (drained at S4/S5)
    bf16x8 B3[4];
    #pragma unroll
    for (int ks = 0; ks < 4; ++ks)
        B3[ks] = *(const bf16x8*)&WselfT[(size_t)(wave * 16 + lr) * 128 + ks * 32 + lg * 8];
    float4 xr[4];
    #pragma unroll
    for (int q = 0; q < 4; ++q) {
        int i = tid + q * 256;
        int r = i >> 4, c4 = i & 15;
        int rg = row0 + r;
        xr[q] = make_float4(0.f, 0.f, 0.f, 0.f);
        if (rg < M) xr[q] = ((const float4*)x)[(size_t)rg * 16 + c4];
    }
    int fr[4][4];
    #pragma unroll
    for (int rt = 0; rt < 4; ++rt)
        #pragma unroll
        for (int j = 0; j < 4; ++j) fr[rt][j] = ldsFlag[rt * 16 + lg * 4 + j];

    // ---- GEMM2: all 64 rows x 16 cols ----
    f32x4 acc2[4];
    #pragma unroll
    for (int rt = 0; rt < 4; ++rt) acc2[rt] = z4;
    #pragma unroll
    for (int ks = 0; ks < 6; ++ks)
        #pragma unroll
        for (int rt = 0; rt < 4; ++rt) {
            bf16x8 af = *(const bf16x8*)&ldsA[(rt * 16 + lr) * 200 + ks * 32 + lg * 8];
            acc2[rt] = __builtin_amdgcn_mfma_f32_16x16x32_bf16(af, B2[ks], acc2[rt], 0, 0, 0);
        }
    const int colg2 = wave * 16 + lr;
    float bb2 = b_aggr[colg2];
    float v[4][4], rp[4][4];
    #pragma unroll
    for (int rt = 0; rt < 4; ++rt)
        #pragma unroll
        for (int j = 0; j < 4; ++j) {
            float t = fr[rt][j] ? 0.f : (acc2[rt][j] + bb2);
            t = (t > 0.f) ? t : 0.01f * t;
            v[rt][j] = t;
            rp[rt][j] = fabsf(t);
        }
    #pragma unroll
    for (int off = 1; off < 16; off <<= 1)
        #pragma unroll
        for (int rt = 0; rt < 4; ++rt)
            #pragma unroll
            for (int j = 0; j < 4; ++j) rp[rt][j] += __shfl_xor(rp[rt][j], off, 64);
    __syncthreads();                                    // S4: all GEMM2 A2-reads done

    // ---- build A3 = [out | x] bf16, stride 136; partial rowmask ----
    #pragma unroll
    for (int rt = 0; rt < 4; ++rt)
        #pragma unroll
        for (int j = 0; j < 4; ++j) {
            int rloc = rt * 16 + lg * 4 + j;
            ldsA[rloc * 136 + colg2] = f2b(v[rt][j]);
            if (lr == 0) ldsP[rloc][wave] = rp[rt][j];
        }
    #pragma unroll
    for (int q = 0; q < 4; ++q) {
        int i = tid + q * 256;
        int r = i >> 4, c4 = i & 15;
        short4 h;
        h.x = f2b(xr[q].x); h.y = f2b(xr[q].y); h.z = f2b(xr[q].z); h.w = f2b(xr[q].w);
        *(short4*)&ldsA[r * 136 + 64 + c4 * 4] = h;
    }
    __syncthreads();                                    // S5: A3 built, B3 arrived

    // issue x fallback loads (consumed after GEMM3)
    float xv[4][4];
    #pragma unroll
    for (int rt = 0; rt < 4; ++rt)
        #pragma unroll
        for (int j = 0; j < 4; ++j) {
            int rg = row0 + rt * 16 + lg * 4 + j;
            xv[rt][j] = (rg < M) ? x[(size_t)rg * 64 + colg2] : 0.f;
        }

    // ---- GEMM3: all 64 rows x 16 cols, K=128 ----
    f32x4 acc3[4];
    #pragma unroll
    for (int rt = 0; rt < 4; ++rt) acc3[rt] = z4;
    #pragma unroll
    for (int ks = 0; ks < 4; ++ks)
        #pragma unroll
        for (int rt = 0; rt < 4; ++rt) {
            bf16x8 af = *(const bf16x8*)&ldsA[(rt * 16 + lr) * 136 + ks * 32 + lg * 8];
            acc3[rt] = __builtin_amdgcn_mfma_f32_16x16x32_bf16(af, B3[ks], acc3[rt], 0, 0, 0);
        }
    // ---- final epilogue: out = flag2 ? x : leaky(Y + b_self) ----
    float bb3 = b_self[colg2];
    #pragma unroll
    for (int rt = 0; rt < 4; ++rt)
        #pragma unroll
        for (int j = 0; j < 4; ++j) {
            int rloc = rt * 16 + lg * 4 + j;
            int rg = row0 + rloc;
            if (rg >= M) continue;
            float4 p = *(const float4*)&ldsP[rloc][0];
            bool f2 = (p.x + p.y + p.z + p.w) == 0.f;
            float t = acc3[rt][j] + bb3;
            t = (t > 0.f) ? t : 0.01f * t;
            out[(size_t)rg * 64 + colg2] = f2 ? xv[rt][j] : t;
        }
}

extern "C" void kernel_launch(void* const* d_in, const int* in_sizes, int n_in,
                              void* d_out, int out_size, void* d_ws, size_t ws_size,
                              hipStream_t stream) {
    const float* x_track      = (const float*)d_in[0];
    const float* x_inter      = (const float*)d_in[1];
    const float* W_conv_ti    = (const float*)d_in[2];
    const float* b_conv_ti    = (const float*)d_in[3];
    const float* W_conv_it    = (const float*)d_in[4];
    const float* b_conv_it    = (const float*)d_in[5];
    const float* W_att_track  = (const float*)d_in[6];
    const float* b_att_track  = (const float*)d_in[7];
    const float* W_aggr_track = (const float*)d_in[8];
    const float* b_aggr_track = (const float*)d_in[9];
    const float* W_att_inter  = (const float*)d_in[10];
    const float* b_att_inter  = (const float*)d_in[11];
    const float* W_aggr_inter = (const float*)d_in[12];
    const float* b_aggr_inter = (const float*)d_in[13];
    const float* W_self_track = (const float*)d_in[14];
    const float* b_self_track = (const float*)d_in[15];
    const float* W_self_inter = (const float*)d_in[16];
    const float* b_self_inter = (const float*)d_in[17];
    const int*   src_ti       = (const int*)d_in[18];
    const int*   dst_ti       = (const int*)d_in[19];
    const int*   src_it       = (const int*)d_in[20];
    const int*   dst_it       = (const int*)d_in[21];

    int NT = in_sizes[0] / DD;
    int NI = in_sizes[1] / DD;
    int E  = in_sizes[18];

    uint8_t* w8 = (uint8_t*)d_ws;
    size_t off = 0;
    auto carve = [&](size_t bytes) -> void* {
        off = (off + 255) & ~(size_t)255;
        void* p = (void*)(w8 + off);
        off += bytes;
        return p;
    };
    unsigned short* y_track = (unsigned short*)carve((size_t)NT * 64 * 2);
    unsigned short* y_inter = (unsigned short*)carve((size_t)NI * 64 * 2);
    short* tot_track = (short*)carve((size_t)NT * 192 * 2);
    short* tot_inter = (short*)carve((size_t)NI * 192 * 2);
    int*   row_in    = (int*)carve((size_t)(NI + 1) * 4);
    int*   row_tr    = (int*)carve((size_t)(NT + 1) * 4);
    int*   bs2       = (int*)carve(128 * 4);           // bsA = bs2, bsB = bs2+64
    size_t zspan     = (size_t)((uint8_t*)(bs2 + 128) - (uint8_t*)row_in);
    int*   cur_in    = (int*)carve((size_t)(NI + 1) * 4);
    int*   cur_tr    = (int*)carve((size_t)(NT + 1) * 4);
    int*   col_ti    = (int*)carve((size_t)E * 4);
    int*   col_it    = (int*)carve((size_t)E * 4);
    int*   flag_tr   = (int*)carve((size_t)NT * 4);
    int*   flag_in   = (int*)carve((size_t)NI * 4);
    short* WattT_tr  = (short*)carve((size_t)192 * 192 * 2);
    short* WaggrT_tr = (short*)carve((size_t)64 * 192 * 2);
    short* WselfT_tr = (short*)carve((size_t)64 * 128 * 2);
    short* WconvT_tr = (short*)carve((size_t)64 * 64 * 2);
    short* WattT_in  = (short*)carve((size_t)192 * 192 * 2);
    short* WaggrT_in = (short*)carve((size_t)64 * 192 * 2);
    short* WselfT_in = (short*)carve((size_t)64 * 128 * 2);
    short* WconvT_in = (short*)carve((size_t)64 * 64 * 2);
    if (off > ws_size) {
        fprintf(stderr, "kernel_launch: ws too small: need %zu have %zu\n", off, ws_size);
        return;
    }

    hipMemsetAsync(row_in, 0, zspan, stream);

    prep_all<<<(122880 + 255) / 256, 256, 0, stream>>>(
        W_att_track, W_aggr_track, W_self_track, W_conv_ti,
        W_att_inter, W_aggr_inter, W_self_inter, W_conv_it,
        WattT_tr, WaggrT_tr, WselfT_tr, WconvT_tr,
        WattT_in, WaggrT_in, WselfT_in, WconvT_in);

    transform_mfma<<<dim3((max(NT, NI) + 255) / 256, 2), 256, 0, stream>>>(
        x_track, WconvT_tr, b_conv_ti, y_track, NT,
        x_inter, WconvT_in, b_conv_it, y_inter, NI);

    int pgrid = 8 * ((E + 256 * EPT - 1) / (256 * EPT));
    hist_part<<<dim3(pgrid, 2), 256, 0, stream>>>(dst_ti, dst_it, E, row_in, row_tr, NI, NT);
    int nb = (max(NT, NI) + SCHUNK - 1) / SCHUNK;
    scan_p1<<<dim3(nb, 2), 256, 0, stream>>>(row_in, NI, bs2, row_tr, NT, bs2 + 64);
    scan_p2<<<2, 64, 0, stream>>>(bs2, bs2 + 64);
    scan_p3<<<dim3(nb, 2), 256, 0, stream>>>(row_in, cur_in, NI, bs2,
                                             row_tr, cur_tr, NT, bs2 + 64);
    permute_part<<<dim3(pgrid, 2), 256, 0, stream>>>(src_ti, dst_ti, cur_in, col_ti,
                                                     src_it, dst_it, cur_tr, col_it,
                                                     E, NI, NT);

    aggregate2<<<dim3((max(NT, NI) + 3) / 4, 2), 256, 0, stream>>>(
        y_track, row_in, col_ti, tot_inter, flag_in, NI,
        y_inter, row_tr, col_it, tot_track, flag_tr, NT);

    float* out = (float*)d_out;
    FusedArgs fa;
    fa.tot[0] = tot_track;  fa.tot[1] = tot_inter;
    fa.x[0] = x_track;      fa.x[1] = x_inter;
    fa.watt[0] = WattT_tr;  fa.watt[1] = WattT_in;
    fa.batt[0] = b_att_track; fa.batt[1] = b_att_inter;
    fa.waggr[0] = WaggrT_tr; fa.waggr[1] = WaggrT_in;
    fa.baggr[0] = b_aggr_track; fa.baggr[1] = b_aggr_inter;
    fa.wself[0] = WselfT_tr; fa.wself[1] = WselfT_in;
    fa.bself[0] = b_self_track; fa.bself[1] = b_self_inter;
    fa.flag[0] = flag_tr;   fa.flag[1] = flag_in;
    fa.out[0] = out;        fa.out[1] = out + (size_t)NT * 64;
    fa.M[0] = NT;           fa.M[1] = NI;
    fused_dense<<<dim3((max(NT, NI) + 63) / 64, 2), 256, 0, stream>>>(fa);
}

// Round 19
// 299.100 us; speedup vs baseline: 1.0379x; 1.0379x over previous
//
#include <hip/hip_runtime.h>
#include <hip/hip_bf16.h>
#include <cstdio>
#include <cstdint>

#define DD 64
#define EPT 8

typedef __attribute__((ext_vector_type(8))) short bf16x8;
typedef __attribute__((ext_vector_type(4))) float f32x4;

__device__ __forceinline__ short f2b(float f) {
    __hip_bfloat16 h = __float2bfloat16(f);
    return __builtin_bit_cast(short, h);
}
__device__ __forceinline__ float b2f(unsigned short s) {
    unsigned u = ((unsigned)s) << 16;
    return __builtin_bit_cast(float, u);
}

// ---------------- front: transform (MFMA) + histogram, fused into one dispatch ----------------
// blocks [0, 2*tpb): transform side = b/tpb ; blocks [2*tpb, 2*tpb+2*pgrid): hist side = vb/pgrid.
// transform and hist are data-independent; prep_all (W_conv^T producer) runs before this kernel.
struct FrontArgs {
    const float* x[2]; const short* WT[2]; const float* bias[2];
    unsigned short* y[2]; int n[2]; int tpb;
    const int* dst[2]; int* row[2]; int hn[2]; int E; int pgrid;
};

__global__ void front(FrontArgs a) {
    const int b = blockIdx.x;
    const int tid = threadIdx.x;
    if (b < 2 * a.tpb) {
        // ---------- transform_mfma body ----------
        const int side = b / a.tpb, bx = b % a.tpb;
        const float* x = a.x[side]; const short* WT = a.WT[side];
        const float* bias = a.bias[side]; unsigned short* y = a.y[side];
        const int n = a.n[side];
        const int wave = tid >> 6, lane = tid & 63;
        const int lr = lane & 15, lg = lane >> 4;
        const int row0 = bx * 256 + wave * 64;
        if (row0 >= n) return;

        bf16x8 B[4][2];
        #pragma unroll
        for (int nt = 0; nt < 4; ++nt)
            #pragma unroll
            for (int ks = 0; ks < 2; ++ks)
                B[nt][ks] = *(const bf16x8*)&WT[(size_t)(nt * 16 + lr) * 64 + ks * 32 + lg * 8];
        float bi[4];
        #pragma unroll
        for (int nt = 0; nt < 4; ++nt) bi[nt] = bias[nt * 16 + lr];

        f32x4 acc[4][4];
        f32x4 z4 = {0.f, 0.f, 0.f, 0.f};
        #pragma unroll
        for (int rt = 0; rt < 4; ++rt)
            #pragma unroll
            for (int nt = 0; nt < 4; ++nt) acc[rt][nt] = z4;

        #pragma unroll
        for (int rt = 0; rt < 4; ++rt) {
            int r = row0 + rt * 16 + lr;
            #pragma unroll
            for (int ks = 0; ks < 2; ++ks) {
                bf16x8 af = {0, 0, 0, 0, 0, 0, 0, 0};
                if (r < n) {
                    const float* p = &x[(size_t)r * 64 + ks * 32 + lg * 8];
                    float4 u0 = *(const float4*)p;
                    float4 u1 = *(const float4*)(p + 4);
                    af[0] = f2b(u0.x); af[1] = f2b(u0.y); af[2] = f2b(u0.z); af[3] = f2b(u0.w);
                    af[4] = f2b(u1.x); af[5] = f2b(u1.y); af[6] = f2b(u1.z); af[7] = f2b(u1.w);
                }
                #pragma unroll
                for (int nt = 0; nt < 4; ++nt)
                    acc[rt][nt] = __builtin_amdgcn_mfma_f32_16x16x32_bf16(af, B[nt][ks], acc[rt][nt], 0, 0, 0);
            }
        }
        #pragma unroll
        for (int rt = 0; rt < 4; ++rt)
            #pragma unroll
            for (int j = 0; j < 4; ++j) {
                int r = row0 + rt * 16 + lg * 4 + j;
                if (r >= n) continue;
                #pragma unroll
                for (int nt = 0; nt < 4; ++nt)
                    y[(size_t)r * 64 + nt * 16 + lr] = (unsigned short)f2b(acc[rt][nt][j] + bi[nt]);
            }
    } else {
        // ---------- hist_part body (int4-vectorized, XCD-partitioned) ----------
        const int vb = b - 2 * a.tpb;
        const int side = vb / a.pgrid, bx = vb % a.pgrid;
        const int* dst = a.dst[side];
        int* row = a.row[side];
        const int n = a.hn[side];
        const int E = a.E;
        int part  = bx & 7;
        int chunk = bx >> 3;
        int psz = (n + 7) >> 3;
        int lo = part * psz, hi = min(n, lo + psz);
        int base = chunk * (256 * EPT) + tid * EPT;
        if (base + EPT <= E) {
            int4 d0 = *(const int4*)&dst[base];
            int4 d1 = *(const int4*)&dst[base + 4];
            int d[8] = { d0.x, d0.y, d0.z, d0.w, d1.x, d1.y, d1.z, d1.w };
            #pragma unroll
            for (int k = 0; k < 8; ++k)
                if (d[k] >= lo && d[k] < hi) atomicAdd(&row[d[k] + 1], 1);
        } else {
            for (int k = 0; k < EPT; ++k) {
                int i = base + k;
                if (i < E) {
                    int dd = dst[i];
                    if (dd >= lo && dd < hi) atomicAdd(&row[dd + 1], 1);
                }
            }
        }
    }
}

// 3-phase multi-block scan over two arrays at once (blockIdx.y selects array).
#define SCHUNK 4096
__global__ void scan_p1(int* __restrict__ rowA, int nA, int* __restrict__ bsA,
                        int* __restrict__ rowB, int nB, int* __restrict__ bsB) {
    int* row = blockIdx.y ? rowB : rowA;
    int n    = blockIdx.y ? nB : nA;
    int* bs  = blockIdx.y ? bsB : bsA;
    int b = blockIdx.x, t = threadIdx.x;
    int base = 1 + b * SCHUNK;
    __shared__ int wsum[4];
    if (base > n) { if (t == 0) bs[b] = 0; return; }
    int idx0 = base + t * 16;
    int v[16];
    int s = 0;
    #pragma unroll
    for (int k = 0; k < 16; ++k) {
        int i = idx0 + k;
        int x = (i <= n) ? row[i] : 0;
        s += x; v[k] = s;
    }
    int lane = t & 63, wid = t >> 6;
    int ssc = s;
    #pragma unroll
    for (int off = 1; off < 64; off <<= 1) {
        int u = __shfl_up(ssc, off, 64);
        if (lane >= off) ssc += u;
    }
    if (lane == 63) wsum[wid] = ssc;
    __syncthreads();
    int wprev = 0;
    #pragma unroll
    for (int w = 0; w < 4; ++w) if (w < wid) wprev += wsum[w];
    int tpre = ssc - s + wprev;
    #pragma unroll
    for (int k = 0; k < 16; ++k) {
        int i = idx0 + k;
        if (i <= n) row[i] = v[k] + tpre;
    }
    if (t == 0) bs[b] = wsum[0] + wsum[1] + wsum[2] + wsum[3];
}

__global__ void scan_p2(int* __restrict__ bsA, int* __restrict__ bsB) {
    int* bs = blockIdx.x ? bsB : bsA;
    int lane = threadIdx.x;   // 64 threads
    int v = bs[lane];
    int s = v;
    #pragma unroll
    for (int off = 1; off < 64; off <<= 1) {
        int u = __shfl_up(s, off, 64);
        if (lane >= off) s += u;
    }
    bs[lane] = s - v;   // exclusive
}

__global__ void scan_p3(int* __restrict__ rowA, int* __restrict__ curA, int nA,
                        const int* __restrict__ bsA,
                        int* __restrict__ rowB, int* __restrict__ curB, int nB,
                        const int* __restrict__ bsB) {
    int* row = blockIdx.y ? rowB : rowA;
    int* cur = blockIdx.y ? curB : curA;
    int n    = blockIdx.y ? nB : nA;
    const int* bs = blockIdx.y ? bsB : bsA;
    int b = blockIdx.x, t = threadIdx.x;
    int base = 1 + b * SCHUNK;
    if (b == 0 && t == 0) { row[0] = 0; cur[0] = 0; }
    if (base > n) return;
    int off = bs[b];
    int end = min(base + SCHUNK - 1, n);
    for (int i = base + t; i <= end; i += 256) {
        int val = row[i] + off;
        row[i] = val;
        if (i < n) cur[i] = val;
    }
}

// ---------------- XCD-partitioned permute (int4-vectorized dst scan; stores src<<6) ----------------
__global__ void permute_part(const int* __restrict__ sti, const int* __restrict__ dti,
                             int* __restrict__ cin, int* __restrict__ oti,
                             const int* __restrict__ sit, const int* __restrict__ dit,
                             int* __restrict__ ctr, int* __restrict__ oit,
                             int E, int nin, int ntr) {
    const int* src; const int* dst; int* cur; int* col; int n;
    if (blockIdx.y == 0) { src = sti; dst = dti; cur = cin; col = oti; n = nin; }
    else                 { src = sit; dst = dit; cur = ctr; col = oit; n = ntr; }
    int part  = blockIdx.x & 7;
    int chunk = blockIdx.x >> 3;
    int psz = (n + 7) >> 3;
    int lo = part * psz, hi = min(n, lo + psz);
    int base = chunk * (256 * EPT) + threadIdx.x * EPT;
    if (base + EPT <= E) {
        int4 d0 = *(const int4*)&dst[base];
        int4 d1 = *(const int4*)&dst[base + 4];
        int d[8] = { d0.x, d0.y, d0.z, d0.w, d1.x, d1.y, d1.z, d1.w };
        #pragma unroll
        for (int k = 0; k < 8; ++k)
            if (d[k] >= lo && d[k] < hi) {
                int p = atomicAdd(&cur[d[k]], 1);
                col[p] = src[base + k] << 6;
            }
    } else {
        for (int k = 0; k < EPT; ++k) {
            int i = base + k;
            if (i < E) {
                int dd = dst[i];
                if (dd >= lo && dd < hi) {
                    int p = atomicAdd(&cur[dd], 1);
                    col[p] = src[i] << 6;
                }
            }
        }
    }
}

// ---------------- aggregate: wave = node; 4 edge slots x 16 lanes; 4-deep gather pipeline ----------------
__global__ void aggregate2(const unsigned short* __restrict__ yt, const int* __restrict__ row_in,
                           const int* __restrict__ col_ti, short* __restrict__ tot_in,
                           int* __restrict__ flag_in, int n_in,
                           const unsigned short* __restrict__ yi, const int* __restrict__ row_tr,
                           const int* __restrict__ col_it, short* __restrict__ tot_tr,
                           int* __restrict__ flag_tr, int n_tr) {
    const unsigned short* y; const int* row; const int* col; short* tot; int* flag; int n;
    if (blockIdx.y == 0) { y = yt; row = row_in; col = col_ti; tot = tot_in; flag = flag_in; n = n_in; }
    else                 { y = yi; row = row_tr; col = col_it; tot = tot_tr; flag = flag_tr; n = n_tr; }
    int wv = (int)((blockIdx.x * (size_t)blockDim.x + threadIdx.x) >> 6);
    if (wv >= n) return;
    int lane = threadIdx.x & 63;
    int sub = lane >> 4;
    int dl4 = (lane & 15) * 4;
    int e0 = row[wv], e1 = row[wv + 1];
    float s0 = 0.f, s1 = 0.f, s2 = 0.f, s3 = 0.f;
    float m0 = 0.f, m1 = 0.f, m2 = 0.f, m3 = 0.f;
    int e = e0 + sub;
    for (; e + 12 < e1; e += 16) {
        int c0 = col[e], c1 = col[e + 4], c2 = col[e + 8], c3 = col[e + 12];
        ushort4 u0 = *(const ushort4*)&y[(size_t)(unsigned)(c0 + dl4)];
        ushort4 u1 = *(const ushort4*)&y[(size_t)(unsigned)(c1 + dl4)];
        ushort4 u2 = *(const ushort4*)&y[(size_t)(unsigned)(c2 + dl4)];
        ushort4 u3 = *(const ushort4*)&y[(size_t)(unsigned)(c3 + dl4)];
        float f;
        f = b2f(u0.x); s0 += f; m0 = fmaxf(m0, f);
        f = b2f(u0.y); s1 += f; m1 = fmaxf(m1, f);
        f = b2f(u0.z); s2 += f; m2 = fmaxf(m2, f);
        f = b2f(u0.w); s3 += f; m3 = fmaxf(m3, f);
        f = b2f(u1.x); s0 += f; m0 = fmaxf(m0, f);
        f = b2f(u1.y); s1 += f; m1 = fmaxf(m1, f);
        f = b2f(u1.z); s2 += f; m2 = fmaxf(m2, f);
        f = b2f(u1.w); s3 += f; m3 = fmaxf(m3, f);
        f = b2f(u2.x); s0 += f; m0 = fmaxf(m0, f);
        f = b2f(u2.y); s1 += f; m1 = fmaxf(m1, f);
        f = b2f(u2.z); s2 += f; m2 = fmaxf(m2, f);
        f = b2f(u2.w); s3 += f; m3 = fmaxf(m3, f);
        f = b2f(u3.x); s0 += f; m0 = fmaxf(m0, f);
        f = b2f(u3.y); s1 += f; m1 = fmaxf(m1, f);
        f = b2f(u3.z); s2 += f; m2 = fmaxf(m2, f);
        f = b2f(u3.w); s3 += f; m3 = fmaxf(m3, f);
    }
    for (; e + 4 < e1; e += 8) {
        int c0 = col[e], c1 = col[e + 4];
        ushort4 u0 = *(const ushort4*)&y[(size_t)(unsigned)(c0 + dl4)];
        ushort4 u1 = *(const ushort4*)&y[(size_t)(unsigned)(c1 + dl4)];
        float f;
        f = b2f(u0.x); s0 += f; m0 = fmaxf(m0, f);
        f = b2f(u0.y); s1 += f; m1 = fmaxf(m1, f);
        f = b2f(u0.z); s2 += f; m2 = fmaxf(m2, f);
        f = b2f(u0.w); s3 += f; m3 = fmaxf(m3, f);
        f = b2f(u1.x); s0 += f; m0 = fmaxf(m0, f);
        f = b2f(u1.y); s1 += f; m1 = fmaxf(m1, f);
        f = b2f(u1.z); s2 += f; m2 = fmaxf(m2, f);
        f = b2f(u1.w); s3 += f; m3 = fmaxf(m3, f);
    }
    for (; e < e1; e += 4) {
        int c0 = col[e];
        ushort4 u0 = *(const ushort4*)&y[(size_t)(unsigned)(c0 + dl4)];
        float f;
        f = b2f(u0.x); s0 += f; m0 = fmaxf(m0, f);
        f = b2f(u0.y); s1 += f; m1 = fmaxf(m1, f);
        f = b2f(u0.z); s2 += f; m2 = fmaxf(m2, f);
        f = b2f(u0.w); s3 += f; m3 = fmaxf(m3, f);
    }
    #pragma unroll
    for (int off = 16; off <= 32; off <<= 1) {
        s0 += __shfl_xor(s0, off, 64); s1 += __shfl_xor(s1, off, 64);
        s2 += __shfl_xor(s2, off, 64); s3 += __shfl_xor(s3, off, 64);
        m0 = fmaxf(m0, __shfl_xor(m0, off, 64)); m1 = fmaxf(m1, __shfl_xor(m1, off, 64));
        m2 = fmaxf(m2, __shfl_xor(m2, off, 64)); m3 = fmaxf(m3, __shfl_xor(m3, off, 64));
    }
    float dn = fmaxf((float)(e1 - e0), 1.0f);
    float a0 = s0 / dn, a1 = s1 / dn, a2 = s2 / dn, a3 = s3 / dn;
    size_t bse = (size_t)wv * 192;
    if (sub == 0) {
        short4 hm = { f2b(a0), f2b(a1), f2b(a2), f2b(a3) };
        short4 hs = { f2b(s0), f2b(s1), f2b(s2), f2b(s3) };
        short4 hx = { f2b(m0), f2b(m1), f2b(m2), f2b(m3) };
        *(short4*)&tot[bse + dl4]       = hm;
        *(short4*)&tot[bse + 64 + dl4]  = hs;
        *(short4*)&tot[bse + 128 + dl4] = hx;
    }
    if (lane == 0) flag[wv] = (e1 == e0) ? 1 : 0;
}

// ---------------- prep all 8 weights: W[K][N] f32 -> W^T[N][K] bf16 ----------------
__global__ void prep_all(const float* __restrict__ Wat_t, const float* __restrict__ Wag_t,
                         const float* __restrict__ Wsf_t, const float* __restrict__ Wcv_t,
                         const float* __restrict__ Wat_i, const float* __restrict__ Wag_i,
                         const float* __restrict__ Wsf_i, const float* __restrict__ Wcv_i,
                         short* __restrict__ oat_t, short* __restrict__ oag_t,
                         short* __restrict__ osf_t, short* __restrict__ ocv_t,
                         short* __restrict__ oat_i, short* __restrict__ oag_i,
                         short* __restrict__ osf_i, short* __restrict__ ocv_i) {
    int i = blockIdx.x * blockDim.x + threadIdx.x;
    if (i >= 122880) return;
    int side = 0;
    if (i >= 61440) { side = 1; i -= 61440; }
    const float* W; short* o; int K, N;
    if (i < 36864)      { W = side ? Wat_i : Wat_t; o = side ? oat_i : oat_t; K = 192; N = 192; }
    else if (i < 49152) { i -= 36864; W = side ? Wag_i : Wag_t; o = side ? oag_i : oag_t; K = 192; N = 64; }
    else if (i < 57344) { i -= 49152; W = side ? Wsf_i : Wsf_t; o = side ? osf_i : osf_t; K = 128; N = 64; }
    else                { i -= 57344; W = side ? Wcv_i : Wcv_t; o = side ? ocv_i : ocv_t; K = 64;  N = 64; }
    int n = i / K, k = i - n * K;
    o[(size_t)n * K + k] = f2b(W[(size_t)k * N + n]);
}

// ---------------- fused dense tail (exact r10 shape): wave = column strip, 64 rows each ----------------
struct FusedArgs {
    const short* tot[2]; const float* x[2];
    const short* watt[2]; const float* batt[2];
    const short* waggr[2]; const float* baggr[2];
    const short* wself[2]; const float* bself[2];
    const int* flag[2]; float* out[2]; int M[2];
};

__launch_bounds__(256, 2)
__global__ void fused_dense(FusedArgs a) {
    const int side = blockIdx.y;
    const int M = a.M[side];
    const int row0 = blockIdx.x * 64;
    if (row0 >= M) return;
    const short* tot = a.tot[side]; const float* x = a.x[side];
    const short* WattT = a.watt[side]; const float* b_att = a.batt[side];
    const short* WaggrT = a.waggr[side]; const float* b_aggr = a.baggr[side];
    const short* WselfT = a.wself[side]; const float* b_self = a.bself[side];
    const int* flag = a.flag[side]; float* out = a.out[side];

    __shared__ __align__(16) short ldsA[64 * 200];
    __shared__ __align__(16) float ldsP[64][4];
    __shared__ int ldsFlag[64];

    const int tid = threadIdx.x;
    const int wave = tid >> 6, lane = tid & 63;
    const int lr = lane & 15, lg = lane >> 4;
    f32x4 z4 = {0.f, 0.f, 0.f, 0.f};

    bf16x8 B1[3][6];
    #pragma unroll
    for (int nt = 0; nt < 3; ++nt)
        #pragma unroll
        for (int ks = 0; ks < 6; ++ks)
            B1[nt][ks] = *(const bf16x8*)&WattT[(size_t)((wave * 3 + nt) * 16 + lr) * 192 + ks * 32 + lg * 8];

    #pragma unroll
    for (int q = 0; q < 6; ++q) {
        int i = tid + q * 256;
        int r = i / 24, c = i % 24;
        int rg = row0 + r;
        uint4 v = {0u, 0u, 0u, 0u};
        if (rg < M) v = ((const uint4*)tot)[(size_t)rg * 24 + c];
        *(uint4*)&ldsA[r * 200 + c * 8] = v;
    }
    if (tid < 64) ldsFlag[tid] = (row0 + tid < M) ? flag[row0 + tid] : 1;
    __syncthreads();                                    // S1

    f32x4 acc1[4][3];
    #pragma unroll
    for (int rt = 0; rt < 4; ++rt)
        #pragma unroll
        for (int nt = 0; nt < 3; ++nt) acc1[rt][nt] = z4;
    #pragma unroll
    for (int ks = 0; ks < 6; ++ks) {
        #pragma unroll
        for (int rt = 0; rt < 4; ++rt) {
            bf16x8 af = *(const bf16x8*)&ldsA[(rt * 16 + lr) * 200 + ks * 32 + lg * 8];
            #pragma unroll
            for (int nt = 0; nt < 3; ++nt)
                acc1[rt][nt] = __builtin_amdgcn_mfma_f32_16x16x32_bf16(af, B1[nt][ks], acc1[rt][nt], 0, 0, 0);
        }
    }
    bf16x8 B2[6];
    #pragma unroll
    for (int ks = 0; ks < 6; ++ks)
        B2[ks] = *(const bf16x8*)&WaggrT[(size_t)(wave * 16 + lr) * 192 + ks * 32 + lg * 8];
    __syncthreads();                                    // S2

    #pragma unroll
    for (int nt = 0; nt < 3; ++nt) {
        int colg = (wave * 3 + nt) * 16 + lr;
        float bb = b_att[colg];
        #pragma unroll
        for (int rt = 0; rt < 4; ++rt)
            #pragma unroll
            for (int j = 0; j < 4; ++j) {
                int rloc = rt * 16 + lg * 4 + j;
                float g = acc1[rt][nt][j] + bb;
                float sg = 1.f / (1.f + __expf(-g));
                int idx = rloc * 200 + colg;
                ldsA[idx] = f2b(b2f((unsigned short)ldsA[idx]) * sg);
            }
    }
    __syncthreads();                                    // S3

    bf16x8 B3[4];
    #pragma unroll
    for (int ks = 0; ks < 4; ++ks)
        B3[ks] = *(const bf16x8*)&WselfT[(size_t)(wave * 16 + lr) * 128 + ks * 32 + lg * 8];
    float4 xr[4];
    #pragma unroll
    for (int q = 0; q < 4; ++q) {
        int i = tid + q * 256;
        int r = i >> 4, c4 = i & 15;
        int rg = row0 + r;
        xr[q] = make_float4(0.f, 0.f, 0.f, 0.f);
        if (rg < M) xr[q] = ((const float4*)x)[(size_t)rg * 16 + c4];
    }
    int fr[4][4];
    #pragma unroll
    for (int rt = 0; rt < 4; ++rt)
        #pragma unroll
        for (int j = 0; j < 4; ++j) fr[rt][j] = ldsFlag[rt * 16 + lg * 4 + j];

    f32x4 acc2[4];
    #pragma unroll
    for (int rt = 0; rt < 4; ++rt) acc2[rt] = z4;
    #pragma unroll
    for (int ks = 0; ks < 6; ++ks)
        #pragma unroll
        for (int rt = 0; rt < 4; ++rt) {
            bf16x8 af = *(const bf16x8*)&ldsA[(rt * 16 + lr) * 200 + ks * 32 + lg * 8];
            acc2[rt] = __builtin_amdgcn_mfma_f32_16x16x32_bf16(af, B2[ks], acc2[rt], 0, 0, 0);
        }
    const int colg2 = wave * 16 + lr;
    float bb2 = b_aggr[colg2];
    float v[4][4], rp[4][4];
    #pragma unroll
    for (int rt = 0; rt < 4; ++rt)
        #pragma unroll
        for (int j = 0; j < 4; ++j) {
            float t = fr[rt][j] ? 0.f : (acc2[rt][j] + bb2);
            t = (t > 0.f) ? t : 0.01f * t;
            v[rt][j] = t;
            rp[rt][j] = fabsf(t);
        }
    #pragma unroll
    for (int off = 1; off < 16; off <<= 1)
        #pragma unroll
        for (int rt = 0; rt < 4; ++rt)
            #pragma unroll
            for (int j = 0; j < 4; ++j) rp[rt][j] += __shfl_xor(rp[rt][j], off, 64);
    __syncthreads();                                    // S4

    #pragma unroll
    for (int rt = 0; rt < 4; ++rt)
        #pragma unroll
        for (int j = 0; j < 4; ++j) {
            int rloc = rt * 16 + lg * 4 + j;
            ldsA[rloc * 136 + colg2] = f2b(v[rt][j]);
            if (lr == 0) ldsP[rloc][wave] = rp[rt][j];
        }
    #pragma unroll
    for (int q = 0; q < 4; ++q) {
        int i = tid + q * 256;
        int r = i >> 4, c4 = i & 15;
        short4 h;
        h.x = f2b(xr[q].x); h.y = f2b(xr[q].y); h.z = f2b(xr[q].z); h.w = f2b(xr[q].w);
        *(short4*)&ldsA[r * 136 + 64 + c4 * 4] = h;
    }
    __syncthreads();                                    // S5

    float xv[4][4];
    #pragma unroll
    for (int rt = 0; rt < 4; ++rt)
        #pragma unroll
        for (int j = 0; j < 4; ++j) {
            int rg = row0 + rt * 16 + lg * 4 + j;
            xv[rt][j] = (rg < M) ? x[(size_t)rg * 64 + colg2] : 0.f;
        }

    f32x4 acc3[4];
    #pragma unroll
    for (int rt = 0; rt < 4; ++rt) acc3[rt] = z4;
    #pragma unroll
    for (int ks = 0; ks < 4; ++ks)
        #pragma unroll
        for (int rt = 0; rt < 4; ++rt) {
            bf16x8 af = *(const bf16x8*)&ldsA[(rt * 16 + lr) * 136 + ks * 32 + lg * 8];
            acc3[rt] = __builtin_amdgcn_mfma_f32_16x16x32_bf16(af, B3[ks], acc3[rt], 0, 0, 0);
        }
    float bb3 = b_self[colg2];
    #pragma unroll
    for (int rt = 0; rt < 4; ++rt)
        #pragma unroll
        for (int j = 0; j < 4; ++j) {
            int rloc = rt * 16 + lg * 4 + j;
            int rg = row0 + rloc;
            if (rg >= M) continue;
            float4 p = *(const float4*)&ldsP[rloc][0];
            bool f2 = (p.x + p.y + p.z + p.w) == 0.f;
            float t = acc3[rt][j] + bb3;
            t = (t > 0.f) ? t : 0.01f * t;
            out[(size_t)rg * 64 + colg2] = f2 ? xv[rt][j] : t;
        }
}

extern "C" void kernel_launch(void* const* d_in, const int* in_sizes, int n_in,
                              void* d_out, int out_size, void* d_ws, size_t ws_size,
                              hipStream_t stream) {
    const float* x_track      = (const float*)d_in[0];
    const float* x_inter      = (const float*)d_in[1];
    const float* W_conv_ti    = (const float*)d_in[2];
    const float* b_conv_ti    = (const float*)d_in[3];
    const float* W_conv_it    = (const float*)d_in[4];
    const float* b_conv_it    = (const float*)d_in[5];
    const float* W_att_track  = (const float*)d_in[6];
    const float* b_att_track  = (const float*)d_in[7];
    const float* W_aggr_track = (const float*)d_in[8];
    const float* b_aggr_track = (const float*)d_in[9];
    const float* W_att_inter  = (const float*)d_in[10];
    const float* b_att_inter  = (const float*)d_in[11];
    const float* W_aggr_inter = (const float*)d_in[12];
    const float* b_aggr_inter = (const float*)d_in[13];
    const float* W_self_track = (const float*)d_in[14];
    const float* b_self_track = (const float*)d_in[15];
    const float* W_self_inter = (const float*)d_in[16];
    const float* b_self_inter = (const float*)d_in[17];
    const int*   src_ti       = (const int*)d_in[18];
    const int*   dst_ti       = (const int*)d_in[19];
    const int*   src_it       = (const int*)d_in[20];
    const int*   dst_it       = (const int*)d_in[21];

    int NT = in_sizes[0] / DD;
    int NI = in_sizes[1] / DD;
    int E  = in_sizes[18];

    uint8_t* w8 = (uint8_t*)d_ws;
    size_t off = 0;
    auto carve = [&](size_t bytes) -> void* {
        off = (off + 255) & ~(size_t)255;
        void* p = (void*)(w8 + off);
        off += bytes;
        return p;
    };
    unsigned short* y_track = (unsigned short*)carve((size_t)NT * 64 * 2);
    unsigned short* y_inter = (unsigned short*)carve((size_t)NI * 64 * 2);
    short* tot_track = (short*)carve((size_t)NT * 192 * 2);
    short* tot_inter = (short*)carve((size_t)NI * 192 * 2);
    int*   row_in    = (int*)carve((size_t)(NI + 1) * 4);
    int*   row_tr    = (int*)carve((size_t)(NT + 1) * 4);
    int*   bs2       = (int*)carve(128 * 4);           // bsA = bs2, bsB = bs2+64
    size_t zspan     = (size_t)((uint8_t*)(bs2 + 128) - (uint8_t*)row_in);
    int*   cur_in    = (int*)carve((size_t)(NI + 1) * 4);
    int*   cur_tr    = (int*)carve((size_t)(NT + 1) * 4);
    int*   col_ti    = (int*)carve((size_t)E * 4);
    int*   col_it    = (int*)carve((size_t)E * 4);
    int*   flag_tr   = (int*)carve((size_t)NT * 4);
    int*   flag_in   = (int*)carve((size_t)NI * 4);
    short* WattT_tr  = (short*)carve((size_t)192 * 192 * 2);
    short* WaggrT_tr = (short*)carve((size_t)64 * 192 * 2);
    short* WselfT_tr = (short*)carve((size_t)64 * 128 * 2);
    short* WconvT_tr = (short*)carve((size_t)64 * 64 * 2);
    short* WattT_in  = (short*)carve((size_t)192 * 192 * 2);
    short* WaggrT_in = (short*)carve((size_t)64 * 192 * 2);
    short* WselfT_in = (short*)carve((size_t)64 * 128 * 2);
    short* WconvT_in = (short*)carve((size_t)64 * 64 * 2);
    if (off > ws_size) {
        fprintf(stderr, "kernel_launch: ws too small: need %zu have %zu\n", off, ws_size);
        return;
    }

    hipMemsetAsync(row_in, 0, zspan, stream);

    prep_all<<<(122880 + 255) / 256, 256, 0, stream>>>(
        W_att_track, W_aggr_track, W_self_track, W_conv_ti,
        W_att_inter, W_aggr_inter, W_self_inter, W_conv_it,
        WattT_tr, WaggrT_tr, WselfT_tr, WconvT_tr,
        WattT_in, WaggrT_in, WselfT_in, WconvT_in);

    // fused transform + histogram (data-independent stages, one dispatch)
    int tpb   = (max(NT, NI) + 255) / 256;
    int pgrid = 8 * ((E + 256 * EPT - 1) / (256 * EPT));
    FrontArgs fr;
    fr.x[0] = x_track;   fr.x[1] = x_inter;
    fr.WT[0] = WconvT_tr; fr.WT[1] = WconvT_in;
    fr.bias[0] = b_conv_ti; fr.bias[1] = b_conv_it;
    fr.y[0] = y_track;   fr.y[1] = y_inter;
    fr.n[0] = NT;        fr.n[1] = NI;
    fr.tpb = tpb;
    fr.dst[0] = dst_ti;  fr.dst[1] = dst_it;
    fr.row[0] = row_in;  fr.row[1] = row_tr;
    fr.hn[0] = NI;       fr.hn[1] = NT;
    fr.E = E;            fr.pgrid = pgrid;
    front<<<2 * tpb + 2 * pgrid, 256, 0, stream>>>(fr);

    int nb = (max(NT, NI) + SCHUNK - 1) / SCHUNK;
    scan_p1<<<dim3(nb, 2), 256, 0, stream>>>(row_in, NI, bs2, row_tr, NT, bs2 + 64);
    scan_p2<<<2, 64, 0, stream>>>(bs2, bs2 + 64);
    scan_p3<<<dim3(nb, 2), 256, 0, stream>>>(row_in, cur_in, NI, bs2,
                                             row_tr, cur_tr, NT, bs2 + 64);
    permute_part<<<dim3(pgrid, 2), 256, 0, stream>>>(src_ti, dst_ti, cur_in, col_ti,
                                                     src_it, dst_it, cur_tr, col_it,
                                                     E, NI, NT);

    aggregate2<<<dim3((max(NT, NI) + 3) / 4, 2), 256, 0, stream>>>(
        y_track, row_in, col_ti, tot_inter, flag_in, NI,
        y_inter, row_tr, col_it, tot_track, flag_tr, NT);

    float* out = (float*)d_out;
    FusedArgs fa;
    fa.tot[0] = tot_track;  fa.tot[1] = tot_inter;
    fa.x[0] = x_track;      fa.x[1] = x_inter;
    fa.watt[0] = WattT_tr;  fa.watt[1] = WattT_in;
    fa.batt[0] = b_att_track; fa.batt[1] = b_att_inter;
    fa.waggr[0] = WaggrT_tr; fa.waggr[1] = WaggrT_in;
    fa.baggr[0] = b_aggr_track; fa.baggr[1] = b_aggr_inter;
    fa.wself[0] = WselfT_tr; fa.wself[1] = WselfT_in;
    fa.bself[0] = b_self_track; fa.bself[1] = b_self_inter;
    fa.flag[0] = flag_tr;   fa.flag[1] = flag_in;
    fa.out[0] = out;        fa.out[1] = out + (size_t)NT * 64;
    fa.M[0] = NT;           fa.M[1] = NI;
    fused_dense<<<dim3((max(NT, NI) + 63) / 64, 2), 256, 0, stream>>>(fa);
}

// Round 20
// 294.831 us; speedup vs baseline: 1.0530x; 1.0145x over previous
//
#include <hip/hip_runtime.h>
#include <hip/hip_bf16.h>
#include <cstdio>
#include <cstdint>

#define DD 64
#define EPT 8

typedef __attribute__((ext_vector_type(8))) short bf16x8;
typedef __attribute__((ext_vector_type(4))) float f32x4;

__device__ __forceinline__ short f2b(float f) {
    __hip_bfloat16 h = __float2bfloat16(f);
    return __builtin_bit_cast(short, h);
}
__device__ __forceinline__ float b2f(unsigned short s) {
    unsigned u = ((unsigned)s) << 16;
    return __builtin_bit_cast(float, u);
}

// ---------------- front: transform (MFMA) + histogram, fused into one dispatch ----------------
struct FrontArgs {
    const float* x[2]; const short* WT[2]; const float* bias[2];
    unsigned short* y[2]; int n[2]; int tpb;
    const int* dst[2]; int* row[2]; int hn[2]; int E; int pgrid;
};

__global__ void front(FrontArgs a) {
    const int b = blockIdx.x;
    const int tid = threadIdx.x;
    if (b < 2 * a.tpb) {
        // ---------- transform_mfma body ----------
        const int side = b / a.tpb, bx = b % a.tpb;
        const float* x = a.x[side]; const short* WT = a.WT[side];
        const float* bias = a.bias[side]; unsigned short* y = a.y[side];
        const int n = a.n[side];
        const int wave = tid >> 6, lane = tid & 63;
        const int lr = lane & 15, lg = lane >> 4;
        const int row0 = bx * 256 + wave * 64;
        if (row0 >= n) return;

        bf16x8 B[4][2];
        #pragma unroll
        for (int nt = 0; nt < 4; ++nt)
            #pragma unroll
            for (int ks = 0; ks < 2; ++ks)
                B[nt][ks] = *(const bf16x8*)&WT[(size_t)(nt * 16 + lr) * 64 + ks * 32 + lg * 8];
        float bi[4];
        #pragma unroll
        for (int nt = 0; nt < 4; ++nt) bi[nt] = bias[nt * 16 + lr];

        f32x4 acc[4][4];
        f32x4 z4 = {0.f, 0.f, 0.f, 0.f};
        #pragma unroll
        for (int rt = 0; rt < 4; ++rt)
            #pragma unroll
            for (int nt = 0; nt < 4; ++nt) acc[rt][nt] = z4;

        #pragma unroll
        for (int rt = 0; rt < 4; ++rt) {
            int r = row0 + rt * 16 + lr;
            #pragma unroll
            for (int ks = 0; ks < 2; ++ks) {
                bf16x8 af = {0, 0, 0, 0, 0, 0, 0, 0};
                if (r < n) {
                    const float* p = &x[(size_t)r * 64 + ks * 32 + lg * 8];
                    float4 u0 = *(const float4*)p;
                    float4 u1 = *(const float4*)(p + 4);
                    af[0] = f2b(u0.x); af[1] = f2b(u0.y); af[2] = f2b(u0.z); af[3] = f2b(u0.w);
                    af[4] = f2b(u1.x); af[5] = f2b(u1.y); af[6] = f2b(u1.z); af[7] = f2b(u1.w);
                }
                #pragma unroll
                for (int nt = 0; nt < 4; ++nt)
                    acc[rt][nt] = __builtin_amdgcn_mfma_f32_16x16x32_bf16(af, B[nt][ks], acc[rt][nt], 0, 0, 0);
            }
        }
        #pragma unroll
        for (int rt = 0; rt < 4; ++rt)
            #pragma unroll
            for (int j = 0; j < 4; ++j) {
                int r = row0 + rt * 16 + lg * 4 + j;
                if (r >= n) continue;
                #pragma unroll
                for (int nt = 0; nt < 4; ++nt)
                    y[(size_t)r * 64 + nt * 16 + lr] = (unsigned short)f2b(acc[rt][nt][j] + bi[nt]);
            }
    } else {
        // ---------- hist_part body (int4-vectorized, XCD-partitioned) ----------
        const int vb = b - 2 * a.tpb;
        const int side = vb / a.pgrid, bx = vb % a.pgrid;
        const int* dst = a.dst[side];
        int* row = a.row[side];
        const int n = a.hn[side];
        const int E = a.E;
        int part  = bx & 7;
        int chunk = bx >> 3;
        int psz = (n + 7) >> 3;
        int lo = part * psz, hi = min(n, lo + psz);
        int base = chunk * (256 * EPT) + tid * EPT;
        if (base + EPT <= E) {
            int4 d0 = *(const int4*)&dst[base];
            int4 d1 = *(const int4*)&dst[base + 4];
            int d[8] = { d0.x, d0.y, d0.z, d0.w, d1.x, d1.y, d1.z, d1.w };
            #pragma unroll
            for (int k = 0; k < 8; ++k)
                if (d[k] >= lo && d[k] < hi) atomicAdd(&row[d[k] + 1], 1);
        } else {
            for (int k = 0; k < EPT; ++k) {
                int i = base + k;
                if (i < E) {
                    int dd = dst[i];
                    if (dd >= lo && dd < hi) atomicAdd(&row[dd + 1], 1);
                }
            }
        }
    }
}

// 2-phase multi-block scan (scan_p2 folded into scan_p3; requires nb <= 64).
#define SCHUNK 4096
__global__ void scan_p1(int* __restrict__ rowA, int nA, int* __restrict__ bsA,
                        int* __restrict__ rowB, int nB, int* __restrict__ bsB) {
    int* row = blockIdx.y ? rowB : rowA;
    int n    = blockIdx.y ? nB : nA;
    int* bs  = blockIdx.y ? bsB : bsA;
    int b = blockIdx.x, t = threadIdx.x;
    int base = 1 + b * SCHUNK;
    __shared__ int wsum[4];
    if (base > n) { if (t == 0) bs[b] = 0; return; }
    int idx0 = base + t * 16;
    int v[16];
    int s = 0;
    #pragma unroll
    for (int k = 0; k < 16; ++k) {
        int i = idx0 + k;
        int x = (i <= n) ? row[i] : 0;
        s += x; v[k] = s;
    }
    int lane = t & 63, wid = t >> 6;
    int ssc = s;
    #pragma unroll
    for (int off = 1; off < 64; off <<= 1) {
        int u = __shfl_up(ssc, off, 64);
        if (lane >= off) ssc += u;
    }
    if (lane == 63) wsum[wid] = ssc;
    __syncthreads();
    int wprev = 0;
    #pragma unroll
    for (int w = 0; w < 4; ++w) if (w < wid) wprev += wsum[w];
    int tpre = ssc - s + wprev;
    #pragma unroll
    for (int k = 0; k < 16; ++k) {
        int i = idx0 + k;
        if (i <= n) row[i] = v[k] + tpre;
    }
    if (t == 0) bs[b] = wsum[0] + wsum[1] + wsum[2] + wsum[3];
}

// scan_p3': each block derives its exclusive prefix from raw bs[] (nb <= 64) in-register.
__global__ void scan_p3(int* __restrict__ rowA, int* __restrict__ curA, int nA,
                        const int* __restrict__ bsA,
                        int* __restrict__ rowB, int* __restrict__ curB, int nB,
                        const int* __restrict__ bsB) {
    int* row = blockIdx.y ? rowB : rowA;
    int* cur = blockIdx.y ? curB : curA;
    int n    = blockIdx.y ? nB : nA;
    const int* bs = blockIdx.y ? bsB : bsA;
    int b = blockIdx.x, t = threadIdx.x;
    __shared__ int s_off;
    if (t < 64) {
        int v = (t < b) ? bs[t] : 0;   // wave 0 computes sum of bs[0..b)
        #pragma unroll
        for (int off = 32; off; off >>= 1) v += __shfl_down(v, off, 64);
        if (t == 0) s_off = v;
    }
    int base = 1 + b * SCHUNK;
    if (b == 0 && t == 0) { row[0] = 0; cur[0] = 0; }
    __syncthreads();
    if (base > n) return;
    int off = s_off;
    int end = min(base + SCHUNK - 1, n);
    for (int i = base + t; i <= end; i += 256) {
        int val = row[i] + off;
        row[i] = val;
        if (i < n) cur[i] = val;
    }
}

// ---------------- XCD-partitioned permute (int4-vectorized dst scan; stores src<<6) ----------------
__global__ void permute_part(const int* __restrict__ sti, const int* __restrict__ dti,
                             int* __restrict__ cin, int* __restrict__ oti,
                             const int* __restrict__ sit, const int* __restrict__ dit,
                             int* __restrict__ ctr, int* __restrict__ oit,
                             int E, int nin, int ntr) {
    const int* src; const int* dst; int* cur; int* col; int n;
    if (blockIdx.y == 0) { src = sti; dst = dti; cur = cin; col = oti; n = nin; }
    else                 { src = sit; dst = dit; cur = ctr; col = oit; n = ntr; }
    int part  = blockIdx.x & 7;
    int chunk = blockIdx.x >> 3;
    int psz = (n + 7) >> 3;
    int lo = part * psz, hi = min(n, lo + psz);
    int base = chunk * (256 * EPT) + threadIdx.x * EPT;
    if (base + EPT <= E) {
        int4 d0 = *(const int4*)&dst[base];
        int4 d1 = *(const int4*)&dst[base + 4];
        int d[8] = { d0.x, d0.y, d0.z, d0.w, d1.x, d1.y, d1.z, d1.w };
        #pragma unroll
        for (int k = 0; k < 8; ++k)
            if (d[k] >= lo && d[k] < hi) {
                int p = atomicAdd(&cur[d[k]], 1);
                col[p] = src[base + k] << 6;
            }
    } else {
        for (int k = 0; k < EPT; ++k) {
            int i = base + k;
            if (i < E) {
                int dd = dst[i];
                if (dd >= lo && dd < hi) {
                    int p = atomicAdd(&cur[dd], 1);
                    col[p] = src[i] << 6;
                }
            }
        }
    }
}

// ---------------- aggregate: wave = node; 4 edge slots x 16 lanes; 4-deep gather pipeline ----------------
__global__ void aggregate2(const unsigned short* __restrict__ yt, const int* __restrict__ row_in,
                           const int* __restrict__ col_ti, short* __restrict__ tot_in,
                           int* __restrict__ flag_in, int n_in,
                           const unsigned short* __restrict__ yi, const int* __restrict__ row_tr,
                           const int* __restrict__ col_it, short* __restrict__ tot_tr,
                           int* __restrict__ flag_tr, int n_tr) {
    const unsigned short* y; const int* row; const int* col; short* tot; int* flag; int n;
    if (blockIdx.y == 0) { y = yt; row = row_in; col = col_ti; tot = tot_in; flag = flag_in; n = n_in; }
    else                 { y = yi; row = row_tr; col = col_it; tot = tot_tr; flag = flag_tr; n = n_tr; }
    int wv = (int)((blockIdx.x * (size_t)blockDim.x + threadIdx.x) >> 6);
    if (wv >= n) return;
    int lane = threadIdx.x & 63;
    int sub = lane >> 4;
    int dl4 = (lane & 15) * 4;
    int e0 = row[wv], e1 = row[wv + 1];
    float s0 = 0.f, s1 = 0.f, s2 = 0.f, s3 = 0.f;
    float m0 = 0.f, m1 = 0.f, m2 = 0.f, m3 = 0.f;
    int e = e0 + sub;
    for (; e + 12 < e1; e += 16) {
        int c0 = col[e], c1 = col[e + 4], c2 = col[e + 8], c3 = col[e + 12];
        ushort4 u0 = *(const ushort4*)&y[(size_t)(unsigned)(c0 + dl4)];
        ushort4 u1 = *(const ushort4*)&y[(size_t)(unsigned)(c1 + dl4)];
        ushort4 u2 = *(const ushort4*)&y[(size_t)(unsigned)(c2 + dl4)];
        ushort4 u3 = *(const ushort4*)&y[(size_t)(unsigned)(c3 + dl4)];
        float f;
        f = b2f(u0.x); s0 += f; m0 = fmaxf(m0, f);
        f = b2f(u0.y); s1 += f; m1 = fmaxf(m1, f);
        f = b2f(u0.z); s2 += f; m2 = fmaxf(m2, f);
        f = b2f(u0.w); s3 += f; m3 = fmaxf(m3, f);
        f = b2f(u1.x); s0 += f; m0 = fmaxf(m0, f);
        f = b2f(u1.y); s1 += f; m1 = fmaxf(m1, f);
        f = b2f(u1.z); s2 += f; m2 = fmaxf(m2, f);
        f = b2f(u1.w); s3 += f; m3 = fmaxf(m3, f);
        f = b2f(u2.x); s0 += f; m0 = fmaxf(m0, f);
        f = b2f(u2.y); s1 += f; m1 = fmaxf(m1, f);
        f = b2f(u2.z); s2 += f; m2 = fmaxf(m2, f);
        f = b2f(u2.w); s3 += f; m3 = fmaxf(m3, f);
        f = b2f(u3.x); s0 += f; m0 = fmaxf(m0, f);
        f = b2f(u3.y); s1 += f; m1 = fmaxf(m1, f);
        f = b2f(u3.z); s2 += f; m2 = fmaxf(m2, f);
        f = b2f(u3.w); s3 += f; m3 = fmaxf(m3, f);
    }
    for (; e + 4 < e1; e += 8) {
        int c0 = col[e], c1 = col[e + 4];
        ushort4 u0 = *(const ushort4*)&y[(size_t)(unsigned)(c0 + dl4)];
        ushort4 u1 = *(const ushort4*)&y[(size_t)(unsigned)(c1 + dl4)];
        float f;
        f = b2f(u0.x); s0 += f; m0 = fmaxf(m0, f);
        f = b2f(u0.y); s1 += f; m1 = fmaxf(m1, f);
        f = b2f(u0.z); s2 += f; m2 = fmaxf(m2, f);
        f = b2f(u0.w); s3 += f; m3 = fmaxf(m3, f);
        f = b2f(u1.x); s0 += f; m0 = fmaxf(m0, f);
        f = b2f(u1.y); s1 += f; m1 = fmaxf(m1, f);
        f = b2f(u1.z); s2 += f; m2 = fmaxf(m2, f);
        f = b2f(u1.w); s3 += f; m3 = fmaxf(m3, f);
    }
    for (; e < e1; e += 4) {
        int c0 = col[e];
        ushort4 u0 = *(const ushort4*)&y[(size_t)(unsigned)(c0 + dl4)];
        float f;
        f = b2f(u0.x); s0 += f; m0 = fmaxf(m0, f);
        f = b2f(u0.y); s1 += f; m1 = fmaxf(m1, f);
        f = b2f(u0.z); s2 += f; m2 = fmaxf(m2, f);
        f = b2f(u0.w); s3 += f; m3 = fmaxf(m3, f);
    }
    #pragma unroll
    for (int off = 16; off <= 32; off <<= 1) {
        s0 += __shfl_xor(s0, off, 64); s1 += __shfl_xor(s1, off, 64);
        s2 += __shfl_xor(s2, off, 64); s3 += __shfl_xor(s3, off, 64);
        m0 = fmaxf(m0, __shfl_xor(m0, off, 64)); m1 = fmaxf(m1, __shfl_xor(m1, off, 64));
        m2 = fmaxf(m2, __shfl_xor(m2, off, 64)); m3 = fmaxf(m3, __shfl_xor(m3, off, 64));
    }
    float dn = fmaxf((float)(e1 - e0), 1.0f);
    float a0 = s0 / dn, a1 = s1 / dn, a2 = s2 / dn, a3 = s3 / dn;
    size_t bse = (size_t)wv * 192;
    if (sub == 0) {
        short4 hm = { f2b(a0), f2b(a1), f2b(a2), f2b(a3) };
        short4 hs = { f2b(s0), f2b(s1), f2b(s2), f2b(s3) };
        short4 hx = { f2b(m0), f2b(m1), f2b(m2), f2b(m3) };
        *(short4*)&tot[bse + dl4]       = hm;
        *(short4*)&tot[bse + 64 + dl4]  = hs;
        *(short4*)&tot[bse + 128 + dl4] = hx;
    }
    if (lane == 0) flag[wv] = (e1 == e0) ? 1 : 0;
}

// ---------------- prep all 8 weights + zero-init CSR counters (memset folded in) ----------------
__global__ void prep_all(const float* __restrict__ Wat_t, const float* __restrict__ Wag_t,
                         const float* __restrict__ Wsf_t, const float* __restrict__ Wcv_t,
                         const float* __restrict__ Wat_i, const float* __restrict__ Wag_i,
                         const float* __restrict__ Wsf_i, const float* __restrict__ Wcv_i,
                         short* __restrict__ oat_t, short* __restrict__ oag_t,
                         short* __restrict__ osf_t, short* __restrict__ ocv_t,
                         short* __restrict__ oat_i, short* __restrict__ oag_i,
                         short* __restrict__ osf_i, short* __restrict__ ocv_i,
                         int* __restrict__ zbase, int zcount) {
    int i = blockIdx.x * blockDim.x + threadIdx.x;
    if (i < zcount) zbase[i] = 0;
    if (i >= 122880) return;
    int side = 0;
    if (i >= 61440) { side = 1; i -= 61440; }
    const float* W; short* o; int K, N;
    if (i < 36864)      { W = side ? Wat_i : Wat_t; o = side ? oat_i : oat_t; K = 192; N = 192; }
    else if (i < 49152) { i -= 36864; W = side ? Wag_i : Wag_t; o = side ? oag_i : oag_t; K = 192; N = 64; }
    else if (i < 57344) { i -= 49152; W = side ? Wsf_i : Wsf_t; o = side ? osf_i : osf_t; K = 128; N = 64; }
    else                { i -= 57344; W = side ? Wcv_i : Wcv_t; o = side ? ocv_i : ocv_t; K = 64;  N = 64; }
    int n = i / K, k = i - n * K;
    o[(size_t)n * K + k] = f2b(W[(size_t)k * N + n]);
}

// ---------------- fused dense tail (exact r10 shape): wave = column strip, 64 rows each ----------------
struct FusedArgs {
    const short* tot[2]; const float* x[2];
    const short* watt[2]; const float* batt[2];
    const short* waggr[2]; const float* baggr[2];
    const short* wself[2]; const float* bself[2];
    const int* flag[2]; float* out[2]; int M[2];
};

__launch_bounds__(256, 2)
__global__ void fused_dense(FusedArgs a) {
    const int side = blockIdx.y;
    const int M = a.M[side];
    const int row0 = blockIdx.x * 64;
    if (row0 >= M) return;
    const short* tot = a.tot[side]; const float* x = a.x[side];
    const short* WattT = a.watt[side]; const float* b_att = a.batt[side];
    const short* WaggrT = a.waggr[side]; const float* b_aggr = a.baggr[side];
    const short* WselfT = a.wself[side]; const float* b_self = a.bself[side];
    const int* flag = a.flag[side]; float* out = a.out[side];

    __shared__ __align__(16) short ldsA[64 * 200];
    __shared__ __align__(16) float ldsP[64][4];
    __shared__ int ldsFlag[64];

    const int tid = threadIdx.x;
    const int wave = tid >> 6, lane = tid & 63;
    const int lr = lane & 15, lg = lane >> 4;
    f32x4 z4 = {0.f, 0.f, 0.f, 0.f};

    bf16x8 B1[3][6];
    #pragma unroll
    for (int nt = 0; nt < 3; ++nt)
        #pragma unroll
        for (int ks = 0; ks < 6; ++ks)
            B1[nt][ks] = *(const bf16x8*)&WattT[(size_t)((wave * 3 + nt) * 16 + lr) * 192 + ks * 32 + lg * 8];

    #pragma unroll
    for (int q = 0; q < 6; ++q) {
        int i = tid + q * 256;
        int r = i / 24, c = i % 24;
        int rg = row0 + r;
        uint4 v = {0u, 0u, 0u, 0u};
        if (rg < M) v = ((const uint4*)tot)[(size_t)rg * 24 + c];
        *(uint4*)&ldsA[r * 200 + c * 8] = v;
    }
    if (tid < 64) ldsFlag[tid] = (row0 + tid < M) ? flag[row0 + tid] : 1;
    __syncthreads();                                    // S1

    f32x4 acc1[4][3];
    #pragma unroll
    for (int rt = 0; rt < 4; ++rt)
        #pragma unroll
        for (int nt = 0; nt < 3; ++nt) acc1[rt][nt] = z4;
    #pragma unroll
    for (int ks = 0; ks < 6; ++ks) {
        #pragma unroll
        for (int rt = 0; rt < 4; ++rt) {
            bf16x8 af = *(const bf16x8*)&ldsA[(rt * 16 + lr) * 200 + ks * 32 + lg * 8];
            #pragma unroll
            for (int nt = 0; nt < 3; ++nt)
                acc1[rt][nt] = __builtin_amdgcn_mfma_f32_16x16x32_bf16(af, B1[nt][ks], acc1[rt][nt], 0, 0, 0);
        }
    }
    bf16x8 B2[6];
    #pragma unroll
    for (int ks = 0; ks < 6; ++ks)
        B2[ks] = *(const bf16x8*)&WaggrT[(size_t)(wave * 16 + lr) * 192 + ks * 32 + lg * 8];
    __syncthreads();                                    // S2

    #pragma unroll
    for (int nt = 0; nt < 3; ++nt) {
        int colg = (wave * 3 + nt) * 16 + lr;
        float bb = b_att[colg];
        #pragma unroll
        for (int rt = 0; rt < 4; ++rt)
            #pragma unroll
            for (int j = 0; j < 4; ++j) {
                int rloc = rt * 16 + lg * 4 + j;
                float g = acc1[rt][nt][j] + bb;
                float sg = 1.f / (1.f + __expf(-g));
                int idx = rloc * 200 + colg;
                ldsA[idx] = f2b(b2f((unsigned short)ldsA[idx]) * sg);
            }
    }
    __syncthreads();                                    // S3

    bf16x8 B3[4];
    #pragma unroll
    for (int ks = 0; ks < 4; ++ks)
        B3[ks] = *(const bf16x8*)&WselfT[(size_t)(wave * 16 + lr) * 128 + ks * 32 + lg * 8];
    float4 xr[4];
    #pragma unroll
    for (int q = 0; q < 4; ++q) {
        int i = tid + q * 256;
        int r = i >> 4, c4 = i & 15;
        int rg = row0 + r;
        xr[q] = make_float4(0.f, 0.f, 0.f, 0.f);
        if (rg < M) xr[q] = ((const float4*)x)[(size_t)rg * 16 + c4];
    }
    int fr[4][4];
    #pragma unroll
    for (int rt = 0; rt < 4; ++rt)
        #pragma unroll
        for (int j = 0; j < 4; ++j) fr[rt][j] = ldsFlag[rt * 16 + lg * 4 + j];

    f32x4 acc2[4];
    #pragma unroll
    for (int rt = 0; rt < 4; ++rt) acc2[rt] = z4;
    #pragma unroll
    for (int ks = 0; ks < 6; ++ks)
        #pragma unroll
        for (int rt = 0; rt < 4; ++rt) {
            bf16x8 af = *(const bf16x8*)&ldsA[(rt * 16 + lr) * 200 + ks * 32 + lg * 8];
            acc2[rt] = __builtin_amdgcn_mfma_f32_16x16x32_bf16(af, B2[ks], acc2[rt], 0, 0, 0);
        }
    const int colg2 = wave * 16 + lr;
    float bb2 = b_aggr[colg2];
    float v[4][4], rp[4][4];
    #pragma unroll
    for (int rt = 0; rt < 4; ++rt)
        #pragma unroll
        for (int j = 0; j < 4; ++j) {
            float t = fr[rt][j] ? 0.f : (acc2[rt][j] + bb2);
            t = (t > 0.f) ? t : 0.01f * t;
            v[rt][j] = t;
            rp[rt][j] = fabsf(t);
        }
    #pragma unroll
    for (int off = 1; off < 16; off <<= 1)
        #pragma unroll
        for (int rt = 0; rt < 4; ++rt)
            #pragma unroll
            for (int j = 0; j < 4; ++j) rp[rt][j] += __shfl_xor(rp[rt][j], off, 64);
    __syncthreads();                                    // S4

    #pragma unroll
    for (int rt = 0; rt < 4; ++rt)
        #pragma unroll
        for (int j = 0; j < 4; ++j) {
            int rloc = rt * 16 + lg * 4 + j;
            ldsA[rloc * 136 + colg2] = f2b(v[rt][j]);
            if (lr == 0) ldsP[rloc][wave] = rp[rt][j];
        }
    #pragma unroll
    for (int q = 0; q < 4; ++q) {
        int i = tid + q * 256;
        int r = i >> 4, c4 = i & 15;
        short4 h;
        h.x = f2b(xr[q].x); h.y = f2b(xr[q].y); h.z = f2b(xr[q].z); h.w = f2b(xr[q].w);
        *(short4*)&ldsA[r * 136 + 64 + c4 * 4] = h;
    }
    __syncthreads();                                    // S5

    float xv[4][4];
    #pragma unroll
    for (int rt = 0; rt < 4; ++rt)
        #pragma unroll
        for (int j = 0; j < 4; ++j) {
            int rg = row0 + rt * 16 + lg * 4 + j;
            xv[rt][j] = (rg < M) ? x[(size_t)rg * 64 + colg2] : 0.f;
        }

    f32x4 acc3[4];
    #pragma unroll
    for (int rt = 0; rt < 4; ++rt) acc3[rt] = z4;
    #pragma unroll
    for (int ks = 0; ks < 4; ++ks)
        #pragma unroll
        for (int rt = 0; rt < 4; ++rt) {
            bf16x8 af = *(const bf16x8*)&ldsA[(rt * 16 + lr) * 136 + ks * 32 + lg * 8];
            acc3[rt] = __builtin_amdgcn_mfma_f32_16x16x32_bf16(af, B3[ks], acc3[rt], 0, 0, 0);
        }
    float bb3 = b_self[colg2];
    #pragma unroll
    for (int rt = 0; rt < 4; ++rt)
        #pragma unroll
        for (int j = 0; j < 4; ++j) {
            int rloc = rt * 16 + lg * 4 + j;
            int rg = row0 + rloc;
            if (rg >= M) continue;
            float4 p = *(const float4*)&ldsP[rloc][0];
            bool f2 = (p.x + p.y + p.z + p.w) == 0.f;
            float t = acc3[rt][j] + bb3;
            t = (t > 0.f) ? t : 0.01f * t;
            out[(size_t)rg * 64 + colg2] = f2 ? xv[rt][j] : t;
        }
}

extern "C" void kernel_launch(void* const* d_in, const int* in_sizes, int n_in,
                              void* d_out, int out_size, void* d_ws, size_t ws_size,
                              hipStream_t stream) {
    const float* x_track      = (const float*)d_in[0];
    const float* x_inter      = (const float*)d_in[1];
    const float* W_conv_ti    = (const float*)d_in[2];
    const float* b_conv_ti    = (const float*)d_in[3];
    const float* W_conv_it    = (const float*)d_in[4];
    const float* b_conv_it    = (const float*)d_in[5];
    const float* W_att_track  = (const float*)d_in[6];
    const float* b_att_track  = (const float*)d_in[7];
    const float* W_aggr_track = (const float*)d_in[8];
    const float* b_aggr_track = (const float*)d_in[9];
    const float* W_att_inter  = (const float*)d_in[10];
    const float* b_att_inter  = (const float*)d_in[11];
    const float* W_aggr_inter = (const float*)d_in[12];
    const float* b_aggr_inter = (const float*)d_in[13];
    const float* W_self_track = (const float*)d_in[14];
    const float* b_self_track = (const float*)d_in[15];
    const float* W_self_inter = (const float*)d_in[16];
    const float* b_self_inter = (const float*)d_in[17];
    const int*   src_ti       = (const int*)d_in[18];
    const int*   dst_ti       = (const int*)d_in[19];
    const int*   src_it       = (const int*)d_in[20];
    const int*   dst_it       = (const int*)d_in[21];

    int NT = in_sizes[0] / DD;
    int NI = in_sizes[1] / DD;
    int E  = in_sizes[18];

    uint8_t* w8 = (uint8_t*)d_ws;
    size_t off = 0;
    auto carve = [&](size_t bytes) -> void* {
        off = (off + 255) & ~(size_t)255;
        void* p = (void*)(w8 + off);
        off += bytes;
        return p;
    };
    unsigned short* y_track = (unsigned short*)carve((size_t)NT * 64 * 2);
    unsigned short* y_inter = (unsigned short*)carve((size_t)NI * 64 * 2);
    short* tot_track = (short*)carve((size_t)NT * 192 * 2);
    short* tot_inter = (short*)carve((size_t)NI * 192 * 2);
    int*   row_in    = (int*)carve((size_t)(NI + 1) * 4);
    int*   row_tr    = (int*)carve((size_t)(NT + 1) * 4);
    int*   bs2       = (int*)carve(128 * 4);           // bsA = bs2, bsB = bs2+64
    size_t zspan     = (size_t)((uint8_t*)(bs2 + 128) - (uint8_t*)row_in);
    int    zcount    = (int)(zspan / 4);
    int*   cur_in    = (int*)carve((size_t)(NI + 1) * 4);
    int*   cur_tr    = (int*)carve((size_t)(NT + 1) * 4);
    int*   col_ti    = (int*)carve((size_t)E * 4);
    int*   col_it    = (int*)carve((size_t)E * 4);
    int*   flag_tr   = (int*)carve((size_t)NT * 4);
    int*   flag_in   = (int*)carve((size_t)NI * 4);
    short* WattT_tr  = (short*)carve((size_t)192 * 192 * 2);
    short* WaggrT_tr = (short*)carve((size_t)64 * 192 * 2);
    short* WselfT_tr = (short*)carve((size_t)64 * 128 * 2);
    short* WconvT_tr = (short*)carve((size_t)64 * 64 * 2);
    short* WattT_in  = (short*)carve((size_t)192 * 192 * 2);
    short* WaggrT_in = (short*)carve((size_t)64 * 192 * 2);
    short* WselfT_in = (short*)carve((size_t)64 * 128 * 2);
    short* WconvT_in = (short*)carve((size_t)64 * 64 * 2);
    if (off > ws_size) {
        fprintf(stderr, "kernel_launch: ws too small: need %zu have %zu\n", off, ws_size);
        return;
    }

    // prep weights + zero CSR counters in one dispatch
    int prep_threads = max(122880, zcount);
    prep_all<<<(prep_threads + 255) / 256, 256, 0, stream>>>(
        W_att_track, W_aggr_track, W_self_track, W_conv_ti,
        W_att_inter, W_aggr_inter, W_self_inter, W_conv_it,
        WattT_tr, WaggrT_tr, WselfT_tr, WconvT_tr,
        WattT_in, WaggrT_in, WselfT_in, WconvT_in,
        row_in, zcount);

    // fused transform + histogram (data-independent stages, one dispatch)
    int tpb   = (max(NT, NI) + 255) / 256;
    int pgrid = 8 * ((E + 256 * EPT - 1) / (256 * EPT));
    FrontArgs fr;
    fr.x[0] = x_track;   fr.x[1] = x_inter;
    fr.WT[0] = WconvT_tr; fr.WT[1] = WconvT_in;
    fr.bias[0] = b_conv_ti; fr.bias[1] = b_conv_it;
    fr.y[0] = y_track;   fr.y[1] = y_inter;
    fr.n[0] = NT;        fr.n[1] = NI;
    fr.tpb = tpb;
    fr.dst[0] = dst_ti;  fr.dst[1] = dst_it;
    fr.row[0] = row_in;  fr.row[1] = row_tr;
    fr.hn[0] = NI;       fr.hn[1] = NT;
    fr.E = E;            fr.pgrid = pgrid;
    front<<<2 * tpb + 2 * pgrid, 256, 0, stream>>>(fr);

    int nb = (max(NT, NI) + SCHUNK - 1) / SCHUNK;   // <= 64 required by scan_p3's in-register prefix
    scan_p1<<<dim3(nb, 2), 256, 0, stream>>>(row_in, NI, bs2, row_tr, NT, bs2 + 64);
    scan_p3<<<dim3(nb, 2), 256, 0, stream>>>(row_in, cur_in, NI, bs2,
                                             row_tr, cur_tr, NT, bs2 + 64);
    permute_part<<<dim3(pgrid, 2), 256, 0, stream>>>(src_ti, dst_ti, cur_in, col_ti,
                                                     src_it, dst_it, cur_tr, col_it,
                                                     E, NI, NT);

    aggregate2<<<dim3((max(NT, NI) + 3) / 4, 2), 256, 0, stream>>>(
        y_track, row_in, col_ti, tot_inter, flag_in, NI,
        y_inter, row_tr, col_it, tot_track, flag_tr, NT);

    float* out = (float*)d_out;
    FusedArgs fa;
    fa.tot[0] = tot_track;  fa.tot[1] = tot_inter;
    fa.x[0] = x_track;      fa.x[1] = x_inter;
    fa.watt[0] = WattT_tr;  fa.watt[1] = WattT_in;
    fa.batt[0] = b_att_track; fa.batt[1] = b_att_inter;
    fa.waggr[0] = WaggrT_tr; fa.waggr[1] = WaggrT_in;
    fa.baggr[0] = b_aggr_track; fa.baggr[1] = b_aggr_inter;
    fa.wself[0] = WselfT_tr; fa.wself[1] = WselfT_in;
    fa.bself[0] = b_self_track; fa.bself[1] = b_self_inter;
    fa.flag[0] = flag_tr;   fa.flag[1] = flag_in;
    fa.out[0] = out;        fa.out[1] = out + (size_t)NT * 64;
    fa.M[0] = NT;           fa.M[1] = NI;
    fused_dense<<<dim3((max(NT, NI) + 63) / 64, 2), 256, 0, stream>>>(fa);
}